// Round 1
// baseline (5275.140 us; speedup 1.0000x reference)
//
#include <hip/hip_runtime.h>
#include <hip/hip_bf16.h>
#include <math.h>

#define BB 8192
#define KK 32
#define DD 768
#define HH 256
#define RR 32
#define SS 4

// ---------------- helpers ----------------
__device__ __forceinline__ float blk_sum256(float v, float* redw) {
  // 256-thread block sum; all threads get the total
  #pragma unroll
  for (int off = 32; off > 0; off >>= 1) v += __shfl_down(v, off, 64);
  __syncthreads();
  if ((threadIdx.x & 63) == 0) redw[threadIdx.x >> 6] = v;
  __syncthreads();
  return redw[0] + redw[1] + redw[2] + redw[3];
}

// ---------------- generic fp32 GEMM ----------------
// C[M,N] = A[M,Kd] * op(W) (+bias[n]) (+addm[m,n])
// TRANSB=1: W is [N,Kd] row-major (C = A @ W^T)
// TRANSB=0: W is [Kd,N] row-major (C = A @ W), row stride assumed == N
template<int TRANSB>
__global__ __launch_bounds__(256) void gemm_tile(
    const float* __restrict__ A, const float* __restrict__ W,
    const float* __restrict__ bias, const float* __restrict__ addm,
    float* __restrict__ C, int M, int N, int Kd)
{
  __shared__ float As[16][64];
  __shared__ float Ws[16][64];
  const int tid = threadIdx.x;
  const int n0 = blockIdx.x * 64;
  const int m0 = blockIdx.y * 64;
  const int l16 = tid & 15, r16 = tid >> 4;
  const int tx = tid & 15, ty = tid >> 4;
  float acc[4][4] = {};
  for (int d0 = 0; d0 < Kd; d0 += 16) {
    #pragma unroll
    for (int i = 0; i < 4; i++)
      As[l16][r16 + 16*i] = A[(size_t)(m0 + r16 + 16*i) * Kd + (d0 + l16)];
    if (TRANSB) {
      #pragma unroll
      for (int i = 0; i < 4; i++)
        Ws[l16][r16 + 16*i] = W[(size_t)(n0 + r16 + 16*i) * Kd + (d0 + l16)];
    } else {
      const int nn = tid & 63, dq = tid >> 6;
      #pragma unroll
      for (int i = 0; i < 4; i++)
        Ws[dq + 4*i][nn] = W[(size_t)(d0 + dq + 4*i) * N + (n0 + nn)];
    }
    __syncthreads();
    #pragma unroll
    for (int dd = 0; dd < 16; dd++) {
      const float4 a4 = *(const float4*)&As[dd][ty*4];
      const float4 b4 = *(const float4*)&Ws[dd][tx*4];
      const float av[4] = {a4.x, a4.y, a4.z, a4.w};
      const float bv[4] = {b4.x, b4.y, b4.z, b4.w};
      #pragma unroll
      for (int i = 0; i < 4; i++)
        #pragma unroll
        for (int j = 0; j < 4; j++)
          acc[i][j] = fmaf(av[i], bv[j], acc[i][j]);
    }
    __syncthreads();
  }
  const int n = n0 + tx*4;
  float4 bi = make_float4(0.f, 0.f, 0.f, 0.f);
  if (bias) bi = *(const float4*)&bias[n];
  #pragma unroll
  for (int i = 0; i < 4; i++) {
    const int m = m0 + ty*4 + i;
    float4 o = make_float4(acc[i][0] + bi.x, acc[i][1] + bi.y,
                           acc[i][2] + bi.z, acc[i][3] + bi.w);
    if (addm) {
      const float4 q4 = *(const float4*)&addm[(size_t)m*N + n];
      o.x += q4.x; o.y += q4.y; o.z += q4.z; o.w += q4.w;
    }
    *(float4*)&C[(size_t)m*N + n] = o;
  }
}

// ---------------- b2 = bv @ Wo^T + bo ----------------
__global__ __launch_bounds__(256) void bias2_kernel(
    const float* __restrict__ Wo, const float* __restrict__ bv,
    const float* __restrict__ bo, float* __restrict__ b2)
{
  const int i = threadIdx.x;
  float s = 0.f;
  for (int hh = 0; hh < HH; hh++) s = fmaf(bv[hh], Wo[(size_t)i*HH + hh], s);
  b2[i] = s + bo[i];
}

// ---------------- attention: e=u.c/16, softmax, cbar ----------------
__global__ __launch_bounds__(256) void attn_kernel(
    const float* __restrict__ c, const float* __restrict__ u,
    float* __restrict__ cbar)
{
  const size_t b = blockIdx.x;
  const int t = threadIdx.x;
  __shared__ float cs[KK*(HH+1)];
  __shared__ float us[HH];
  __shared__ float red2[8][32];
  __shared__ float att[KK];
  const float* cb = c + b*KK*HH;
  for (int i = t; i < KK*HH; i += 256) cs[(i>>8)*257 + (i&255)] = cb[i];
  us[t] = u[b*HH + t];
  __syncthreads();
  const int k = t & 31, j = t >> 5;
  float p = 0.f;
  #pragma unroll
  for (int i = 0; i < 32; i++) { const int d = j*32 + i; p = fmaf(us[d], cs[k*257 + d], p); }
  red2[j][k] = p;
  __syncthreads();
  if (t < KK) {
    float ev = 0.f;
    #pragma unroll
    for (int jj = 0; jj < 8; jj++) ev += red2[jj][t];
    ev *= 0.0625f;   // 1/sqrt(H)
    float m = ev;
    #pragma unroll
    for (int off = 16; off > 0; off >>= 1) m = fmaxf(m, __shfl_xor(m, off, 32));
    const float ex = expf(ev - m);
    float s = ex;
    #pragma unroll
    for (int off = 16; off > 0; off >>= 1) s += __shfl_xor(s, off, 32);
    att[t] = ex / s;
  }
  __syncthreads();
  float acc = 0.f;
  #pragma unroll
  for (int k2 = 0; k2 < KK; k2++) acc = fmaf(att[k2], cs[k2*257 + t], acc);
  cbar[b*HH + t] = acc;
}

// ---------------- LayerNorm over H ----------------
__global__ __launch_bounds__(256) void ln_kernel(
    const float* __restrict__ X, const float* __restrict__ g,
    const float* __restrict__ bb, float* __restrict__ out)
{
  __shared__ float redw[4];
  const size_t row = blockIdx.x;
  const int t = threadIdx.x;
  const float x = X[row*HH + t];
  const float mu = blk_sum256(x, redw) * (1.f/HH);
  const float d = x - mu;
  const float var = blk_sum256(d*d, redw) * (1.f/HH);
  out[row*HH + t] = d / sqrtf(var + 1e-5f) * g[t] + bb[t];
}

// ---------------- rowwise l2norm (in place, 256 cols) ----------------
__global__ __launch_bounds__(256) void l2row_kernel(float* __restrict__ X)
{
  __shared__ float redw[4];
  const size_t row = blockIdx.x;
  const int t = threadIdx.x;
  const float x = X[row*HH + t];
  const float n2 = blk_sum256(x*x, redw);
  X[row*HH + t] = x / fmaxf(sqrtf(n2), 1e-12f);
}

// ---------------- dpp = l2norm(cn @ W_dpp^T), 8 rows/block ----------------
__global__ __launch_bounds__(256) void dpp_kernel(
    const float* __restrict__ cn, const float* __restrict__ Wd,
    float* __restrict__ dpp)
{
  __shared__ float wds[RR*(HH+1)];
  __shared__ float rows[8*(HH+1)];
  const int t = threadIdx.x;
  for (int i = t; i < RR*HH; i += 256) wds[(i>>8)*257 + (i&255)] = Wd[i];
  const size_t m0 = (size_t)blockIdx.x * 8;
  for (int i = t; i < 8*HH; i += 256)
    rows[(i>>8)*257 + (i&255)] = cn[(m0 + (i>>8))*HH + (i&255)];
  __syncthreads();
  const int mi = t >> 5, r = t & 31;
  float p = 0.f;
  for (int d = 0; d < HH; d++) p = fmaf(rows[mi*257 + d], wds[r*257 + d], p);
  float sq = p*p;
  #pragma unroll
  for (int off = 16; off > 0; off >>= 1) sq += __shfl_xor(sq, off, 32);
  const float sc = 1.f / fmaxf(sqrtf(sq), 1e-12f);
  dpp[(m0 + mi)*RR + r] = p * sc;
}

// ---------------- per-step: he, base, gain, mask, logits, msim, chosen ----------------
__global__ __launch_bounds__(256) void step_kernel(
    const float* __restrict__ h, const float* __restrict__ cn,
    const float* __restrict__ dpp, const float* __restrict__ se,
    const int* __restrict__ labels, const float* __restrict__ lam_in,
    float* __restrict__ logits, float* __restrict__ msim,
    float* __restrict__ chosen, const int step)
{
  __shared__ float hes[HH];
  __shared__ float cns[KK*(HH+1)];
  __shared__ float dps[KK*(RR+1)];
  __shared__ float red2[8][32];
  __shared__ float redw[4];
  const size_t b = blockIdx.x;
  const int t = threadIdx.x;
  const float* cnb = cn + b*KK*HH;
  const float* dpb = dpp + b*KK*RR;
  for (int i = t; i < KK*HH; i += 256) cns[(i>>8)*257 + (i&255)] = cnb[i];
  for (int i = t; i < KK*RR; i += 256) dps[(i>>5)*33 + (i&31)] = dpb[i];
  const float hv = h[b*HH + t] + se[step*HH + t];   // step < MAX_SHOT always
  const float n2 = blk_sum256(hv*hv, redw);         // syncs inside
  hes[t] = hv / fmaxf(sqrtf(n2), 1e-12f);
  __syncthreads();
  const int k = t & 31, j = t >> 5;
  float p = 0.f;
  #pragma unroll
  for (int i = 0; i < 32; i++) { const int d = j*32 + i; p = fmaf(hes[d], cns[k*257 + d], p); }
  red2[j][k] = p;
  __syncthreads();
  if (t < KK) {
    float base = 0.f;
    #pragma unroll
    for (int jj = 0; jj < 8; jj++) base += red2[jj][t];
    float sc = base * 10.0f;   // 1/TEMP
    if (step > 0) {
      const float x = lam_in[0];
      const float lam = (x > 0.f) ? (x + log1pf(expf(-x))) : log1pf(expf(x));
      const float ms = msim[b*KK + t];
      sc += lam * logf(1e-6f + 1.f - fminf(ms*ms, 0.999f));
    }
    for (int js = 0; js < step; js++)
      if (labels[b*SS + js] == t) sc = -100.f;
    logits[(b*SS + step)*KK + t] = sc;
  }
  if (step < SS - 1) {
    const int idx = labels[b*SS + step];
    chosen[b*HH + t] = cns[idx*257 + t];
    __syncthreads();   // msim reads above must complete before write
    if (t < KK) {
      float dn = 0.f;
      #pragma unroll
      for (int r = 0; r < RR; r++) dn = fmaf(dps[t*33 + r], dps[idx*33 + r], dn);
      const float old = (step == 0) ? -1e30f : msim[b*KK + t];
      msim[b*KK + t] = fmaxf(old, dn);
    }
  }
}

// ---------------- GRU combine + l2norm ----------------
__global__ __launch_bounds__(256) void gru_kernel(
    const float* __restrict__ gi, const float* __restrict__ gh,
    float* __restrict__ h)
{
  __shared__ float redw[4];
  const size_t b = blockIdx.x;
  const int t = threadIdx.x;
  const size_t g0 = b * (size_t)(3*HH);
  const float ir = gi[g0 + t], iz = gi[g0 + HH + t], inn = gi[g0 + 2*HH + t];
  const float hr = gh[g0 + t], hz = gh[g0 + HH + t], hn  = gh[g0 + 2*HH + t];
  const float r = 1.f / (1.f + expf(-(ir + hr)));
  const float z = 1.f / (1.f + expf(-(iz + hz)));
  const float n = tanhf(inn + r * hn);
  const float hv = h[b*HH + t];
  const float o = (1.f - z) * n + z * hv;
  const float n2 = blk_sum256(o*o, redw);
  h[b*HH + t] = o / fmaxf(sqrtf(n2), 1e-12f);
}

// ---------------- argmax + log-softmax loss ----------------
__global__ __launch_bounds__(256) void loss_kernel(
    const float* __restrict__ logits, const int* __restrict__ labels,
    float* __restrict__ preds, float* __restrict__ loss)
{
  const int i = blockIdx.x * 256 + threadIdx.x;   // < BB*SS
  const float* row = logits + (size_t)i * KK;
  float m = -1e30f; int arg = 0;
  #pragma unroll
  for (int k2 = 0; k2 < KK; k2++) {
    const float v = row[k2];
    if (v > m) { m = v; arg = k2; }
  }
  preds[i] = (float)arg;
  const float mx = fmaxf(m, -100.f);
  float se = 0.f, sl = 0.f;
  #pragma unroll
  for (int k2 = 0; k2 < KK; k2++) {
    const float li = fmaxf(row[k2], -100.f);
    se += expf(li - mx);
    sl += li;
  }
  const float lse = mx + logf(se);
  const int lab = labels[i];
  const float nll = lse - fmaxf(row[lab], -100.f);
  const float smooth = lse - sl * (1.f/KK);
  float contrib = (0.9f * nll + 0.1f * smooth) * (1.f / (BB*SS));
  #pragma unroll
  for (int off = 32; off > 0; off >>= 1) contrib += __shfl_down(contrib, off, 64);
  if ((threadIdx.x & 63) == 0) atomicAdd(loss, contrib);
}

// ---------------- launch ----------------
extern "C" void kernel_launch(void* const* d_in, const int* in_sizes, int n_in,
                              void* d_out, int out_size, void* d_ws, size_t ws_size,
                              hipStream_t stream)
{
  const float* query_emb  = (const float*)d_in[0];
  const float* cand_emb   = (const float*)d_in[1];
  const int*   labels     = (const int*)d_in[2];
  const float* W_in       = (const float*)d_in[3];
  const float* attn_in_w  = (const float*)d_in[4];
  const float* attn_in_b  = (const float*)d_in[5];
  const float* attn_out_w = (const float*)d_in[6];
  const float* attn_out_b = (const float*)d_in[7];
  const float* ln_g       = (const float*)d_in[8];
  const float* ln_b       = (const float*)d_in[9];
  const float* Wq         = (const float*)d_in[10];
  const float* Wc         = (const float*)d_in[11];
  const float* gru_wih    = (const float*)d_in[12];
  const float* gru_whh    = (const float*)d_in[13];
  const float* gru_bih    = (const float*)d_in[14];
  const float* gru_bhh    = (const float*)d_in[15];
  const float* step_emb   = (const float*)d_in[16];
  const float* W_dpp      = (const float*)d_in[17];
  const float* dpp_lam    = (const float*)d_in[18];

  float* out    = (float*)d_out;
  float* logits = out;
  float* preds  = out + (size_t)BB*SS*KK;
  float* loss   = preds + (size_t)BB*SS;

  // workspace layout (floats): ~626 MB total
  float* wsf  = (float*)d_ws;
  float* c_   = wsf;                          // 262144*256
  float* cn_  = c_   + (size_t)BB*KK*HH;      // 262144*256
  float* dpp_ = cn_  + (size_t)BB*KK*HH;      // 262144*32
  float* q_   = dpp_ + (size_t)BB*KK*RR;      // 8192*256
  float* bufA = q_   + (size_t)BB*HH;         // 8192*256
  float* bufB = bufA + (size_t)BB*HH;         // 8192*256 (h lives here)
  float* bufC = bufB + (size_t)BB*HH;         // 8192*256 (chosen)
  float* gi_  = bufC + (size_t)BB*HH;         // 8192*768
  float* gh_  = gi_  + (size_t)BB*3*HH;       // 8192*768
  float* ms_  = gh_  + (size_t)BB*3*HH;       // 8192*32
  float* M2_  = ms_  + (size_t)BB*KK;         // 256*256
  float* b2_  = M2_  + (size_t)HH*HH;         // 256

  hipMemsetAsync(loss, 0, sizeof(float), stream);

  const dim3 blk(256);

  // precompute fused attention-output weights: M2 = Wo @ Wvp, b2 = bv@Wo^T + bo
  gemm_tile<0><<<dim3(4, 4), blk, 0, stream>>>(attn_out_w, attn_in_w + 512*HH,
                                               nullptr, nullptr, M2_, HH, HH, HH);
  bias2_kernel<<<1, blk, 0, stream>>>(attn_out_w, attn_in_b + 2*HH, attn_out_b, b2_);

  // q = query_emb @ W_in^T ; c = cand_emb @ W_in^T
  gemm_tile<1><<<dim3(4, BB/64), blk, 0, stream>>>(query_emb, W_in, nullptr, nullptr,
                                                   q_, BB, HH, DD);
  gemm_tile<1><<<dim3(4, BB*KK/64), blk, 0, stream>>>(cand_emb, W_in, nullptr, nullptr,
                                                      c_, BB*KK, HH, DD);
  // qh = q @ Wqp^T + bq ; u = qh @ Wkp   (qh.bk shift cancels in softmax)
  gemm_tile<1><<<dim3(4, BB/64), blk, 0, stream>>>(q_, attn_in_w, attn_in_b, nullptr,
                                                   bufA, BB, HH, HH);
  gemm_tile<0><<<dim3(4, BB/64), blk, 0, stream>>>(bufA, attn_in_w + HH*HH, nullptr, nullptr,
                                                   bufB, BB, HH, HH);
  // attention -> cbar
  attn_kernel<<<BB, blk, 0, stream>>>(c_, bufB, bufA);
  // x = cbar @ M2^T + b2 + q
  gemm_tile<1><<<dim3(4, BB/64), blk, 0, stream>>>(bufA, M2_, b2_, q_, bufB, BB, HH, HH);
  // enh = LN(x)
  ln_kernel<<<BB, blk, 0, stream>>>(bufB, ln_g, ln_b, bufA);
  // h = l2norm(enh @ Wq^T)
  gemm_tile<1><<<dim3(4, BB/64), blk, 0, stream>>>(bufA, Wq, nullptr, nullptr, bufB, BB, HH, HH);
  l2row_kernel<<<BB, blk, 0, stream>>>(bufB);
  // cand_n = l2norm(c @ Wc^T) ; dpp = l2norm(cand_n @ W_dpp^T)
  gemm_tile<1><<<dim3(4, BB*KK/64), blk, 0, stream>>>(c_, Wc, nullptr, nullptr,
                                                      cn_, BB*KK, HH, HH);
  l2row_kernel<<<BB*KK, blk, 0, stream>>>(cn_);
  dpp_kernel<<<BB*KK/8, blk, 0, stream>>>(cn_, W_dpp, dpp_);

  for (int step = 0; step < SS; step++) {
    step_kernel<<<BB, blk, 0, stream>>>(bufB, cn_, dpp_, step_emb, labels, dpp_lam,
                                        logits, ms_, bufC, step);
    if (step < SS - 1) {   // h after last step is unused
      gemm_tile<1><<<dim3(12, BB/64), blk, 0, stream>>>(bufC, gru_wih, gru_bih, nullptr,
                                                        gi_, BB, 3*HH, HH);
      gemm_tile<1><<<dim3(12, BB/64), blk, 0, stream>>>(bufB, gru_whh, gru_bhh, nullptr,
                                                        gh_, BB, 3*HH, HH);
      gru_kernel<<<BB, blk, 0, stream>>>(gi_, gh_, bufB);
    }
  }
  loss_kernel<<<BB*SS/256, blk, 0, stream>>>(logits, labels, preds, loss);
}

// Round 2
// 3734.298 us; speedup vs baseline: 1.4126x; 1.4126x over previous
//
#include <hip/hip_runtime.h>
#include <hip/hip_bf16.h>
#include <math.h>

#define BB 8192
#define KK 32
#define DD 768
#define HH 256
#define RR 32
#define SS 4

// ---------------- helpers ----------------
__device__ __forceinline__ float blk_sum256(float v, float* redw) {
  #pragma unroll
  for (int off = 32; off > 0; off >>= 1) v += __shfl_down(v, off, 64);
  __syncthreads();
  if ((threadIdx.x & 63) == 0) redw[threadIdx.x >> 6] = v;
  __syncthreads();
  return redw[0] + redw[1] + redw[2] + redw[3];
}

// ---------------- big fp32 GEMM: 128x128 tile, 8x8 per thread ----------------
// C[M,N] = A[M,Kd] * op(W) (+bias[n]) (+addm[m,n])
// TRANSB=1: W is [N,Kd] (C = A @ W^T);  TRANSB=0: W is [Kd,N] (C = A @ W)
// Requires M%128==0, N%128==0, Kd%16==0.
template<int TRANSB>
__global__ __launch_bounds__(256) void gemm128(
    const float* __restrict__ A, const float* __restrict__ W,
    const float* __restrict__ bias, const float* __restrict__ addm,
    float* __restrict__ C, int M, int N, int Kd)
{
  __shared__ float As[16][132];   // stride 132: 132%32==4 -> conflict-free col-stores
  __shared__ float Bs[16][132];
  const int tid = threadIdx.x;
  const int n0 = blockIdx.x * 128;
  const int m0 = blockIdx.y * 128;
  const int tx = tid & 15, ty = tid >> 4;
  float acc[8][8] = {};
  const int sm = tid >> 1;          // 0..127
  const int sk = (tid & 1) * 8;     // 0 or 8

  for (int k0 = 0; k0 < Kd; k0 += 16) {
    {
      const float* ap = &A[(size_t)(m0 + sm) * Kd + k0 + sk];
      const float4 a0 = *(const float4*)ap;
      const float4 a1 = *(const float4*)(ap + 4);
      As[sk+0][sm] = a0.x; As[sk+1][sm] = a0.y; As[sk+2][sm] = a0.z; As[sk+3][sm] = a0.w;
      As[sk+4][sm] = a1.x; As[sk+5][sm] = a1.y; As[sk+6][sm] = a1.z; As[sk+7][sm] = a1.w;
    }
    if (TRANSB) {
      const float* wp = &W[(size_t)(n0 + sm) * Kd + k0 + sk];
      const float4 b0 = *(const float4*)wp;
      const float4 b1 = *(const float4*)(wp + 4);
      Bs[sk+0][sm] = b0.x; Bs[sk+1][sm] = b0.y; Bs[sk+2][sm] = b0.z; Bs[sk+3][sm] = b0.w;
      Bs[sk+4][sm] = b1.x; Bs[sk+5][sm] = b1.y; Bs[sk+6][sm] = b1.z; Bs[sk+7][sm] = b1.w;
    } else {
      const int dn = (tid & 31) * 4, dk = tid >> 5;
      const float4 b0 = *(const float4*)&W[(size_t)(k0 + dk) * N + n0 + dn];
      const float4 b1 = *(const float4*)&W[(size_t)(k0 + dk + 8) * N + n0 + dn];
      *(float4*)&Bs[dk][dn]     = b0;
      *(float4*)&Bs[dk + 8][dn] = b1;
    }
    __syncthreads();
    #pragma unroll
    for (int dd = 0; dd < 16; dd++) {
      float a[8], b[8];
      *(float4*)&a[0] = *(const float4*)&As[dd][ty*4];
      *(float4*)&a[4] = *(const float4*)&As[dd][ty*4 + 64];
      *(float4*)&b[0] = *(const float4*)&Bs[dd][tx*4];
      *(float4*)&b[4] = *(const float4*)&Bs[dd][tx*4 + 64];
      #pragma unroll
      for (int i = 0; i < 8; i++)
        #pragma unroll
        for (int j = 0; j < 8; j++)
          acc[i][j] = fmaf(a[i], b[j], acc[i][j]);
    }
    __syncthreads();
  }

  #pragma unroll
  for (int jg = 0; jg < 2; jg++) {
    const int n = n0 + tx*4 + jg*64;
    float4 bi = make_float4(0.f, 0.f, 0.f, 0.f);
    if (bias) bi = *(const float4*)&bias[n];
    #pragma unroll
    for (int ig = 0; ig < 2; ig++)
      #pragma unroll
      for (int i = 0; i < 4; i++) {
        const int m = m0 + ty*4 + ig*64 + i;
        float4 o = make_float4(acc[ig*4+i][jg*4+0] + bi.x,
                               acc[ig*4+i][jg*4+1] + bi.y,
                               acc[ig*4+i][jg*4+2] + bi.z,
                               acc[ig*4+i][jg*4+3] + bi.w);
        if (addm) {
          const float4 q4 = *(const float4*)&addm[(size_t)m*N + n];
          o.x += q4.x; o.y += q4.y; o.z += q4.z; o.w += q4.w;
        }
        *(float4*)&C[(size_t)m*N + n] = o;
      }
  }
}

// ---------------- small fp32 GEMM: 64x64 tile (padded LDS) ----------------
template<int TRANSB>
__global__ __launch_bounds__(256) void gemm_tile(
    const float* __restrict__ A, const float* __restrict__ W,
    const float* __restrict__ bias, const float* __restrict__ addm,
    float* __restrict__ C, int M, int N, int Kd)
{
  __shared__ float As[16][68];   // 68%32==4 -> staging col-stores 2-way (free)
  __shared__ float Ws[16][68];
  const int tid = threadIdx.x;
  const int n0 = blockIdx.x * 64;
  const int m0 = blockIdx.y * 64;
  const int l16 = tid & 15, r16 = tid >> 4;
  const int tx = tid & 15, ty = tid >> 4;
  float acc[4][4] = {};
  for (int d0 = 0; d0 < Kd; d0 += 16) {
    #pragma unroll
    for (int i = 0; i < 4; i++)
      As[l16][r16 + 16*i] = A[(size_t)(m0 + r16 + 16*i) * Kd + (d0 + l16)];
    if (TRANSB) {
      #pragma unroll
      for (int i = 0; i < 4; i++)
        Ws[l16][r16 + 16*i] = W[(size_t)(n0 + r16 + 16*i) * Kd + (d0 + l16)];
    } else {
      const int nn = tid & 63, dq = tid >> 6;
      #pragma unroll
      for (int i = 0; i < 4; i++)
        Ws[dq + 4*i][nn] = W[(size_t)(d0 + dq + 4*i) * N + (n0 + nn)];
    }
    __syncthreads();
    #pragma unroll
    for (int dd = 0; dd < 16; dd++) {
      const float4 a4 = *(const float4*)&As[dd][ty*4];
      const float4 b4 = *(const float4*)&Ws[dd][tx*4];
      const float av[4] = {a4.x, a4.y, a4.z, a4.w};
      const float bv[4] = {b4.x, b4.y, b4.z, b4.w};
      #pragma unroll
      for (int i = 0; i < 4; i++)
        #pragma unroll
        for (int j = 0; j < 4; j++)
          acc[i][j] = fmaf(av[i], bv[j], acc[i][j]);
    }
    __syncthreads();
  }
  const int n = n0 + tx*4;
  float4 bi = make_float4(0.f, 0.f, 0.f, 0.f);
  if (bias) bi = *(const float4*)&bias[n];
  #pragma unroll
  for (int i = 0; i < 4; i++) {
    const int m = m0 + ty*4 + i;
    float4 o = make_float4(acc[i][0] + bi.x, acc[i][1] + bi.y,
                           acc[i][2] + bi.z, acc[i][3] + bi.w);
    if (addm) {
      const float4 q4 = *(const float4*)&addm[(size_t)m*N + n];
      o.x += q4.x; o.y += q4.y; o.z += q4.z; o.w += q4.w;
    }
    *(float4*)&C[(size_t)m*N + n] = o;
  }
}

// ---------------- b2 = bv @ Wo^T + bo ----------------
__global__ __launch_bounds__(256) void bias2_kernel(
    const float* __restrict__ Wo, const float* __restrict__ bv,
    const float* __restrict__ bo, float* __restrict__ b2)
{
  const int i = threadIdx.x;
  float s = 0.f;
  for (int hh = 0; hh < HH; hh++) s = fmaf(bv[hh], Wo[(size_t)i*HH + hh], s);
  b2[i] = s + bo[i];
}

// ---------------- attention: e=u.c/16, softmax, cbar ----------------
__global__ __launch_bounds__(256) void attn_kernel(
    const float* __restrict__ c, const float* __restrict__ u,
    float* __restrict__ cbar)
{
  const size_t b = blockIdx.x;
  const int t = threadIdx.x;
  __shared__ float cs[KK*(HH+1)];
  __shared__ float us[HH];
  __shared__ float red2[8][32];
  __shared__ float att[KK];
  const float* cb = c + b*KK*HH;
  for (int i = t; i < KK*HH; i += 256) cs[(i>>8)*257 + (i&255)] = cb[i];
  us[t] = u[b*HH + t];
  __syncthreads();
  const int k = t & 31, j = t >> 5;
  float p = 0.f;
  #pragma unroll
  for (int i = 0; i < 32; i++) { const int d = j*32 + i; p = fmaf(us[d], cs[k*257 + d], p); }
  red2[j][k] = p;
  __syncthreads();
  if (t < KK) {
    float ev = 0.f;
    #pragma unroll
    for (int jj = 0; jj < 8; jj++) ev += red2[jj][t];
    ev *= 0.0625f;
    float m = ev;
    #pragma unroll
    for (int off = 16; off > 0; off >>= 1) m = fmaxf(m, __shfl_xor(m, off, 32));
    const float ex = expf(ev - m);
    float s = ex;
    #pragma unroll
    for (int off = 16; off > 0; off >>= 1) s += __shfl_xor(s, off, 32);
    att[t] = ex / s;
  }
  __syncthreads();
  float acc = 0.f;
  #pragma unroll
  for (int k2 = 0; k2 < KK; k2++) acc = fmaf(att[k2], cs[k2*257 + t], acc);
  cbar[b*HH + t] = acc;
}

// ---------------- LayerNorm over H ----------------
__global__ __launch_bounds__(256) void ln_kernel(
    const float* __restrict__ X, const float* __restrict__ g,
    const float* __restrict__ bb, float* __restrict__ out)
{
  __shared__ float redw[4];
  const size_t row = blockIdx.x;
  const int t = threadIdx.x;
  const float x = X[row*HH + t];
  const float mu = blk_sum256(x, redw) * (1.f/HH);
  const float d = x - mu;
  const float var = blk_sum256(d*d, redw) * (1.f/HH);
  out[row*HH + t] = d / sqrtf(var + 1e-5f) * g[t] + bb[t];
}

// ---------------- rowwise l2norm (in place, 256 cols) ----------------
__global__ __launch_bounds__(256) void l2row_kernel(float* __restrict__ X)
{
  __shared__ float redw[4];
  const size_t row = blockIdx.x;
  const int t = threadIdx.x;
  const float x = X[row*HH + t];
  const float n2 = blk_sum256(x*x, redw);
  X[row*HH + t] = x / fmaxf(sqrtf(n2), 1e-12f);
}

// ---------------- dpp = l2norm(cn @ W_dpp^T), 8 rows/block ----------------
__global__ __launch_bounds__(256) void dpp_kernel(
    const float* __restrict__ cn, const float* __restrict__ Wd,
    float* __restrict__ dpp)
{
  __shared__ float wds[RR*(HH+1)];
  __shared__ float rows[8*(HH+1)];
  const int t = threadIdx.x;
  for (int i = t; i < RR*HH; i += 256) wds[(i>>8)*257 + (i&255)] = Wd[i];
  const size_t m0 = (size_t)blockIdx.x * 8;
  for (int i = t; i < 8*HH; i += 256)
    rows[(i>>8)*257 + (i&255)] = cn[(m0 + (i>>8))*HH + (i&255)];
  __syncthreads();
  const int mi = t >> 5, r = t & 31;
  float p = 0.f;
  for (int d = 0; d < HH; d++) p = fmaf(rows[mi*257 + d], wds[r*257 + d], p);
  float sq = p*p;
  #pragma unroll
  for (int off = 16; off > 0; off >>= 1) sq += __shfl_xor(sq, off, 32);
  const float sc = 1.f / fmaxf(sqrtf(sq), 1e-12f);
  dpp[(m0 + mi)*RR + r] = p * sc;
}

// ---------------- per-step: he, base, gain, mask, logits, msim, chosen ----------------
__global__ __launch_bounds__(256) void step_kernel(
    const float* __restrict__ h, const float* __restrict__ cn,
    const float* __restrict__ dpp, const float* __restrict__ se,
    const int* __restrict__ labels, const float* __restrict__ lam_in,
    float* __restrict__ logits, float* __restrict__ msim,
    float* __restrict__ chosen, const int step)
{
  __shared__ float hes[HH];
  __shared__ float cns[KK*(HH+1)];
  __shared__ float dps[KK*(RR+1)];
  __shared__ float red2[8][32];
  __shared__ float redw[4];
  const size_t b = blockIdx.x;
  const int t = threadIdx.x;
  const float* cnb = cn + b*KK*HH;
  const float* dpb = dpp + b*KK*RR;
  for (int i = t; i < KK*HH; i += 256) cns[(i>>8)*257 + (i&255)] = cnb[i];
  for (int i = t; i < KK*RR; i += 256) dps[(i>>5)*33 + (i&31)] = dpb[i];
  const float hv = h[b*HH + t] + se[step*HH + t];
  const float n2 = blk_sum256(hv*hv, redw);
  hes[t] = hv / fmaxf(sqrtf(n2), 1e-12f);
  __syncthreads();
  const int k = t & 31, j = t >> 5;
  float p = 0.f;
  #pragma unroll
  for (int i = 0; i < 32; i++) { const int d = j*32 + i; p = fmaf(hes[d], cns[k*257 + d], p); }
  red2[j][k] = p;
  __syncthreads();
  if (t < KK) {
    float base = 0.f;
    #pragma unroll
    for (int jj = 0; jj < 8; jj++) base += red2[jj][t];
    float sc = base * 10.0f;
    if (step > 0) {
      const float x = lam_in[0];
      const float lam = (x > 0.f) ? (x + log1pf(expf(-x))) : log1pf(expf(x));
      const float ms = msim[b*KK + t];
      sc += lam * logf(1e-6f + 1.f - fminf(ms*ms, 0.999f));
    }
    for (int js = 0; js < step; js++)
      if (labels[b*SS + js] == t) sc = -100.f;
    logits[(b*SS + step)*KK + t] = sc;
  }
  if (step < SS - 1) {
    const int idx = labels[b*SS + step];
    chosen[b*HH + t] = cns[idx*257 + t];
    __syncthreads();
    if (t < KK) {
      float dn = 0.f;
      #pragma unroll
      for (int r = 0; r < RR; r++) dn = fmaf(dps[t*33 + r], dps[idx*33 + r], dn);
      const float old = (step == 0) ? -1e30f : msim[b*KK + t];
      msim[b*KK + t] = fmaxf(old, dn);
    }
  }
}

// ---------------- GRU combine + l2norm ----------------
__global__ __launch_bounds__(256) void gru_kernel(
    const float* __restrict__ gi, const float* __restrict__ gh,
    float* __restrict__ h)
{
  __shared__ float redw[4];
  const size_t b = blockIdx.x;
  const int t = threadIdx.x;
  const size_t g0 = b * (size_t)(3*HH);
  const float ir = gi[g0 + t], iz = gi[g0 + HH + t], inn = gi[g0 + 2*HH + t];
  const float hr = gh[g0 + t], hz = gh[g0 + HH + t], hn  = gh[g0 + 2*HH + t];
  const float r = 1.f / (1.f + expf(-(ir + hr)));
  const float z = 1.f / (1.f + expf(-(iz + hz)));
  const float n = tanhf(inn + r * hn);
  const float hv = h[b*HH + t];
  const float o = (1.f - z) * n + z * hv;
  const float n2 = blk_sum256(o*o, redw);
  h[b*HH + t] = o / fmaxf(sqrtf(n2), 1e-12f);
}

// ---------------- argmax + log-softmax loss ----------------
__global__ __launch_bounds__(256) void loss_kernel(
    const float* __restrict__ logits, const int* __restrict__ labels,
    float* __restrict__ preds, float* __restrict__ loss)
{
  const int i = blockIdx.x * 256 + threadIdx.x;
  const float* row = logits + (size_t)i * KK;
  float m = -1e30f; int arg = 0;
  #pragma unroll
  for (int k2 = 0; k2 < KK; k2++) {
    const float v = row[k2];
    if (v > m) { m = v; arg = k2; }
  }
  preds[i] = (float)arg;
  const float mx = fmaxf(m, -100.f);
  float se = 0.f, sl = 0.f;
  #pragma unroll
  for (int k2 = 0; k2 < KK; k2++) {
    const float li = fmaxf(row[k2], -100.f);
    se += expf(li - mx);
    sl += li;
  }
  const float lse = mx + logf(se);
  const int lab = labels[i];
  const float nll = lse - fmaxf(row[lab], -100.f);
  const float smooth = lse - sl * (1.f/KK);
  float contrib = (0.9f * nll + 0.1f * smooth) * (1.f / (BB*SS));
  #pragma unroll
  for (int off = 32; off > 0; off >>= 1) contrib += __shfl_down(contrib, off, 64);
  if ((threadIdx.x & 63) == 0) atomicAdd(loss, contrib);
}

// ---------------- launch ----------------
extern "C" void kernel_launch(void* const* d_in, const int* in_sizes, int n_in,
                              void* d_out, int out_size, void* d_ws, size_t ws_size,
                              hipStream_t stream)
{
  const float* query_emb  = (const float*)d_in[0];
  const float* cand_emb   = (const float*)d_in[1];
  const int*   labels     = (const int*)d_in[2];
  const float* W_in       = (const float*)d_in[3];
  const float* attn_in_w  = (const float*)d_in[4];
  const float* attn_in_b  = (const float*)d_in[5];
  const float* attn_out_w = (const float*)d_in[6];
  const float* attn_out_b = (const float*)d_in[7];
  const float* ln_g       = (const float*)d_in[8];
  const float* ln_b       = (const float*)d_in[9];
  const float* Wq         = (const float*)d_in[10];
  const float* Wc         = (const float*)d_in[11];
  const float* gru_wih    = (const float*)d_in[12];
  const float* gru_whh    = (const float*)d_in[13];
  const float* gru_bih    = (const float*)d_in[14];
  const float* gru_bhh    = (const float*)d_in[15];
  const float* step_emb   = (const float*)d_in[16];
  const float* W_dpp      = (const float*)d_in[17];
  const float* dpp_lam    = (const float*)d_in[18];

  float* out    = (float*)d_out;
  float* logits = out;
  float* preds  = out + (size_t)BB*SS*KK;
  float* loss   = preds + (size_t)BB*SS;

  float* wsf  = (float*)d_ws;
  float* c_   = wsf;
  float* cn_  = c_   + (size_t)BB*KK*HH;
  float* dpp_ = cn_  + (size_t)BB*KK*HH;
  float* q_   = dpp_ + (size_t)BB*KK*RR;
  float* bufA = q_   + (size_t)BB*HH;
  float* bufB = bufA + (size_t)BB*HH;
  float* bufC = bufB + (size_t)BB*HH;
  float* gi_  = bufC + (size_t)BB*HH;
  float* gh_  = gi_  + (size_t)BB*3*HH;
  float* ms_  = gh_  + (size_t)BB*3*HH;
  float* M2_  = ms_  + (size_t)BB*KK;
  float* b2_  = M2_  + (size_t)HH*HH;

  hipMemsetAsync(loss, 0, sizeof(float), stream);

  const dim3 blk(256);

  // M2 = Wo @ Wvp ; b2 = bv@Wo^T + bo
  gemm_tile<0><<<dim3(4, 4), blk, 0, stream>>>(attn_out_w, attn_in_w + 512*HH,
                                               nullptr, nullptr, M2_, HH, HH, HH);
  bias2_kernel<<<1, blk, 0, stream>>>(attn_out_w, attn_in_b + 2*HH, attn_out_b, b2_);

  // q = query_emb @ W_in^T ; c = cand_emb @ W_in^T
  gemm_tile<1><<<dim3(4, BB/64), blk, 0, stream>>>(query_emb, W_in, nullptr, nullptr,
                                                   q_, BB, HH, DD);
  gemm128<1><<<dim3(2, BB*KK/128), blk, 0, stream>>>(cand_emb, W_in, nullptr, nullptr,
                                                     c_, BB*KK, HH, DD);
  // qh = q @ Wqp^T + bq ; u = qh @ Wkp
  gemm_tile<1><<<dim3(4, BB/64), blk, 0, stream>>>(q_, attn_in_w, attn_in_b, nullptr,
                                                   bufA, BB, HH, HH);
  gemm_tile<0><<<dim3(4, BB/64), blk, 0, stream>>>(bufA, attn_in_w + HH*HH, nullptr, nullptr,
                                                   bufB, BB, HH, HH);
  attn_kernel<<<BB, blk, 0, stream>>>(c_, bufB, bufA);
  // x = cbar @ M2^T + b2 + q
  gemm_tile<1><<<dim3(4, BB/64), blk, 0, stream>>>(bufA, M2_, b2_, q_, bufB, BB, HH, HH);
  ln_kernel<<<BB, blk, 0, stream>>>(bufB, ln_g, ln_b, bufA);
  // h = l2norm(enh @ Wq^T)
  gemm_tile<1><<<dim3(4, BB/64), blk, 0, stream>>>(bufA, Wq, nullptr, nullptr, bufB, BB, HH, HH);
  l2row_kernel<<<BB, blk, 0, stream>>>(bufB);
  // cand_n = l2norm(c @ Wc^T) ; dpp = l2norm(cand_n @ W_dpp^T)
  gemm128<1><<<dim3(2, BB*KK/128), blk, 0, stream>>>(c_, Wc, nullptr, nullptr,
                                                     cn_, BB*KK, HH, HH);
  l2row_kernel<<<BB*KK, blk, 0, stream>>>(cn_);
  dpp_kernel<<<BB*KK/8, blk, 0, stream>>>(cn_, W_dpp, dpp_);

  for (int step = 0; step < SS; step++) {
    step_kernel<<<BB, blk, 0, stream>>>(bufB, cn_, dpp_, step_emb, labels, dpp_lam,
                                        logits, ms_, bufC, step);
    if (step < SS - 1) {
      gemm128<1><<<dim3(6, BB/128), blk, 0, stream>>>(bufC, gru_wih, gru_bih, nullptr,
                                                      gi_, BB, 3*HH, HH);
      gemm128<1><<<dim3(6, BB/128), blk, 0, stream>>>(bufB, gru_whh, gru_bhh, nullptr,
                                                      gh_, BB, 3*HH, HH);
      gru_kernel<<<BB, blk, 0, stream>>>(gi_, gh_, bufB);
    }
  }
  loss_kernel<<<BB*SS/256, blk, 0, stream>>>(logits, labels, preds, loss);
}